// Round 1
// baseline (1112.545 us; speedup 1.0000x reference)
//
#include <hip/hip_runtime.h>
#include <hip/hip_bf16.h>

#define FPS_THREADS 1024
#define PTS_PER_THR 16      // 16384 / 1024

// ---------------------------------------------------------------------------
// helpers
// ---------------------------------------------------------------------------
__device__ inline unsigned long long shfl_down_u64(unsigned long long x, int off) {
    unsigned int lo = (unsigned int)(x & 0xFFFFFFFFull);
    unsigned int hi = (unsigned int)(x >> 32);
    lo = __shfl_down(lo, off, 64);
    hi = __shfl_down(hi, off, 64);
    return (((unsigned long long)hi) << 32) | lo;
}

// ---------------------------------------------------------------------------
// 1. Farthest point sampling: one block per batch, points cached in registers
//    writes cp_idx (ws) and control_points (d_out region 2)
// ---------------------------------------------------------------------------
__global__ __launch_bounds__(FPS_THREADS) void fps_kernel(
        const float* __restrict__ src, int* __restrict__ cp_idx,
        float* __restrict__ out_cp, int N, int K) {
    const int b = blockIdx.x;
    const int t = threadIdx.x;
    const float* p = src + (size_t)b * N * 3;

    float px[PTS_PER_THR], py[PTS_PER_THR], pz[PTS_PER_THR], dmin[PTS_PER_THR];
#pragma unroll
    for (int i = 0; i < PTS_PER_THR; ++i) {
        int j = i * FPS_THREADS + t;
        px[i] = p[j * 3 + 0];
        py[i] = p[j * 3 + 1];
        pz[i] = p[j * 3 + 2];
        dmin[i] = __builtin_huge_valf();
    }

    __shared__ unsigned long long red[FPS_THREADS / 64];
    __shared__ float sC[3];

    if (t == 0) {
        cp_idx[b * K + 0] = 0;
        float fx = p[0], fy = p[1], fz = p[2];
        out_cp[(b * K + 0) * 3 + 0] = fx;
        out_cp[(b * K + 0) * 3 + 1] = fy;
        out_cp[(b * K + 0) * 3 + 2] = fz;
        sC[0] = fx; sC[1] = fy; sC[2] = fz;
    }
    __syncthreads();

    for (int k = 1; k < K; ++k) {
        const float cx = sC[0], cy = sC[1], cz = sC[2];
        unsigned long long best = 0ull;
#pragma unroll
        for (int i = 0; i < PTS_PER_THR; ++i) {
            float dx = px[i] - cx, dy = py[i] - cy, dz = pz[i] - cz;
            float d = dx * dx + dy * dy + dz * dz;
            dmin[i] = fminf(dmin[i], d);
            unsigned int fb = __float_as_uint(dmin[i]);   // nonneg -> monotonic bits
            unsigned int j = (unsigned int)(i * FPS_THREADS + t);
            unsigned long long pk =
                (((unsigned long long)fb) << 32) | (0xFFFFFFFFu - j); // tie -> smaller j
            best = (pk > best) ? pk : best;
        }
#pragma unroll
        for (int off = 32; off >= 1; off >>= 1) {
            unsigned long long o = shfl_down_u64(best, off);
            best = (o > best) ? o : best;
        }
        if ((t & 63) == 0) red[t >> 6] = best;
        __syncthreads();
        if (t == 0) {
            unsigned long long bb = red[0];
#pragma unroll
            for (int wv = 1; wv < FPS_THREADS / 64; ++wv)
                bb = (red[wv] > bb) ? red[wv] : bb;
            int far = (int)(0xFFFFFFFFu - (unsigned int)(bb & 0xFFFFFFFFull));
            cp_idx[b * K + k] = far;
            float fx = p[far * 3 + 0], fy = p[far * 3 + 1], fz = p[far * 3 + 2];
            out_cp[(b * K + k) * 3 + 0] = fx;
            out_cp[(b * K + k) * 3 + 1] = fy;
            out_cp[(b * K + k) * 3 + 2] = fz;
            sC[0] = fx; sC[1] = fy; sC[2] = fz;
        }
        __syncthreads();
    }
}

// ---------------------------------------------------------------------------
// 2. Nearest target point per control point: one block per (b,k)
// ---------------------------------------------------------------------------
__global__ __launch_bounds__(256) void nn_kernel(
        const float* __restrict__ tgt, const float* __restrict__ cp,
        int* __restrict__ nn_idx, int M) {
    const int bk = blockIdx.x;          // b*K + k
    const int b = bk >> 7;              // K = 128
    const int t = threadIdx.x;
    const float* tp = tgt + (size_t)b * M * 3;

    const float cx = cp[bk * 3 + 0], cy = cp[bk * 3 + 1], cz = cp[bk * 3 + 2];
    const float cp2 = cx * cx + cy * cy + cz * cz;

    unsigned long long best = ~0ull;
    for (int m = t; m < M; m += 256) {
        float tx = tp[m * 3 + 0], ty = tp[m * 3 + 1], tz = tp[m * 3 + 2];
        float tg2 = tx * tx + ty * ty + tz * tz;
        float cross = cx * tx + cy * ty + cz * tz;
        float v = (cp2 + tg2) - 2.0f * cross;
        unsigned int fb = __float_as_uint(v);
        fb = (fb & 0x80000000u) ? ~fb : (fb | 0x80000000u); // order-preserving flip
        unsigned long long pk = (((unsigned long long)fb) << 32) | (unsigned int)m;
        best = (pk < best) ? pk : best;   // min value, tie -> smaller m
    }
#pragma unroll
    for (int off = 32; off >= 1; off >>= 1) {
        unsigned long long o = shfl_down_u64(best, off);
        best = (o < best) ? o : best;
    }
    __shared__ unsigned long long red[4];
    if ((t & 63) == 0) red[t >> 6] = best;
    __syncthreads();
    if (t == 0) {
        unsigned long long bb = red[0];
        for (int wv = 1; wv < 4; ++wv) bb = (red[wv] < bb) ? red[wv] : bb;
        nn_idx[bk] = (int)(bb & 0xFFFFFFFFull);
    }
}

// ---------------------------------------------------------------------------
// 3. Gather [control_feats | tgt_local_feats] -> mlp_in (B*K, 2F)
// ---------------------------------------------------------------------------
__global__ __launch_bounds__(256) void gather_kernel(
        const float* __restrict__ src_feats, const float* __restrict__ tgt_feats,
        const int* __restrict__ cp_idx, const int* __restrict__ nn_idx,
        float* __restrict__ mlp_in, int N, int M, int F) {
    const int r = blockIdx.x;           // b*K + k
    const int b = r >> 7;
    const int t = threadIdx.x;
    const float4* a = reinterpret_cast<const float4*>(
        src_feats + ((size_t)b * N + cp_idx[r]) * F);
    const float4* c = reinterpret_cast<const float4*>(
        tgt_feats + ((size_t)b * M + nn_idx[r]) * F);
    float4* o = reinterpret_cast<float4*>(mlp_in + (size_t)r * 2 * F);
    o[t] = a[t];            // F/4 = 256 = blockDim
    o[256 + t] = c[t];
}

// ---------------------------------------------------------------------------
// 4. f32 tiled GEMM with bias: C(MxN) = A(MxK) @ B(KxN) + bias
//    BM=BN=64, BK=16, 256 threads, 4x4 per thread
// ---------------------------------------------------------------------------
__global__ __launch_bounds__(256) void gemm_bias(
        const float* __restrict__ A, const float* __restrict__ B,
        const float* __restrict__ bias, float* __restrict__ C,
        int M, int N, int K) {
    __shared__ float As[16][68];
    __shared__ float Bs[16][68];
    const int tid = threadIdx.x;
    const int row0 = blockIdx.y * 64;
    const int col0 = blockIdx.x * 64;

    const int tr = (tid >> 4) * 4;      // 0..60
    const int tc = (tid & 15) * 4;      // 0..60
    const int arow = tid >> 2, ak4 = (tid & 3) * 4;
    const int brow = tid >> 4, bc4 = (tid & 15) * 4;

    float acc[4][4];
#pragma unroll
    for (int i = 0; i < 4; ++i)
#pragma unroll
        for (int j = 0; j < 4; ++j) acc[i][j] = 0.f;

    for (int kt = 0; kt < K; kt += 16) {
        float4 av = *reinterpret_cast<const float4*>(
            &A[(size_t)(row0 + arow) * K + kt + ak4]);
        float4 bv = *reinterpret_cast<const float4*>(
            &B[(size_t)(kt + brow) * N + col0 + bc4]);
        __syncthreads();
        As[ak4 + 0][arow] = av.x;
        As[ak4 + 1][arow] = av.y;
        As[ak4 + 2][arow] = av.z;
        As[ak4 + 3][arow] = av.w;
        *reinterpret_cast<float4*>(&Bs[brow][bc4]) = bv;
        __syncthreads();
#pragma unroll
        for (int kk = 0; kk < 16; ++kk) {
            float a0 = As[kk][tr + 0], a1 = As[kk][tr + 1];
            float a2 = As[kk][tr + 2], a3 = As[kk][tr + 3];
            float b0 = Bs[kk][tc + 0], b1 = Bs[kk][tc + 1];
            float b2 = Bs[kk][tc + 2], b3 = Bs[kk][tc + 3];
            acc[0][0] += a0 * b0; acc[0][1] += a0 * b1; acc[0][2] += a0 * b2; acc[0][3] += a0 * b3;
            acc[1][0] += a1 * b0; acc[1][1] += a1 * b1; acc[1][2] += a1 * b2; acc[1][3] += a1 * b3;
            acc[2][0] += a2 * b0; acc[2][1] += a2 * b1; acc[2][2] += a2 * b2; acc[2][3] += a2 * b3;
            acc[3][0] += a3 * b0; acc[3][1] += a3 * b1; acc[3][2] += a3 * b2; acc[3][3] += a3 * b3;
        }
    }
#pragma unroll
    for (int i = 0; i < 4; ++i) {
        float* crow = &C[(size_t)(row0 + tr + i) * N + col0 + tc];
#pragma unroll
        for (int j = 0; j < 4; ++j) crow[j] = acc[i][j] + bias[col0 + tc + j];
    }
}

// ---------------------------------------------------------------------------
// 5. BatchNorm column stats (two-pass) over Mrows x Ncols row-major
// ---------------------------------------------------------------------------
__global__ __launch_bounds__(256) void bn_stats(
        const float* __restrict__ Hm, float* __restrict__ mu,
        float* __restrict__ rstd, int Mrows, int Ncols) {
    const int c = blockIdx.x * 256 + threadIdx.x;
    if (c >= Ncols) return;
    float s = 0.f;
    for (int r = 0; r < Mrows; ++r) s += Hm[(size_t)r * Ncols + c];
    const float m = s / (float)Mrows;
    float v = 0.f;
    for (int r = 0; r < Mrows; ++r) {
        float d = Hm[(size_t)r * Ncols + c] - m;
        v += d * d;
    }
    v /= (float)Mrows;
    mu[c] = m;
    rstd[c] = rsqrtf(v + 1e-5f);
}

// ---------------------------------------------------------------------------
// 6. BN apply + ReLU (in place)
// ---------------------------------------------------------------------------
__global__ __launch_bounds__(256) void bn_apply(
        float* __restrict__ Hm, const float* __restrict__ mu,
        const float* __restrict__ rstd, const float* __restrict__ g,
        const float* __restrict__ beta, int total, int NcolsMask) {
    const int i = blockIdx.x * 256 + threadIdx.x;
    if (i < total) {
        const int c = i & NcolsMask;
        float x = Hm[i];
        x = g[c] * (x - mu[c]) * rstd[c] + beta[c];
        Hm[i] = fmaxf(x, 0.f);
    }
}

// ---------------------------------------------------------------------------
// 7. Head: w (1024x3) = h2 (1024x512) @ W3 (512x3) + b3 ; one wave per row
// ---------------------------------------------------------------------------
__global__ __launch_bounds__(256) void head_kernel(
        const float* __restrict__ Hm, const float* __restrict__ W3,
        const float* __restrict__ b3, float* __restrict__ w_out, int Ncols) {
    const int row = blockIdx.x * 4 + (threadIdx.x >> 6);
    const int lane = threadIdx.x & 63;
    float a0 = 0.f, a1 = 0.f, a2 = 0.f;
    for (int c = lane; c < Ncols; c += 64) {
        float h = Hm[(size_t)row * Ncols + c];
        a0 += h * W3[c * 3 + 0];
        a1 += h * W3[c * 3 + 1];
        a2 += h * W3[c * 3 + 2];
    }
#pragma unroll
    for (int off = 32; off >= 1; off >>= 1) {
        a0 += __shfl_down(a0, off, 64);
        a1 += __shfl_down(a1, off, 64);
        a2 += __shfl_down(a2, off, 64);
    }
    if (lane == 0) {
        w_out[row * 3 + 0] = a0 + b3[0];
        w_out[row * 3 + 1] = a1 + b3[1];
        w_out[row * 3 + 2] = a2 + b3[2];
    }
}

// ---------------------------------------------------------------------------
// 8. RBF softmax interpolation: output = src + (softmax(-2*d2) @ w)
// ---------------------------------------------------------------------------
__global__ __launch_bounds__(256) void rbf_kernel(
        const float* __restrict__ src, const float* __restrict__ cp,
        const float* __restrict__ w, float* __restrict__ outp,
        float* __restrict__ delta, int N, int K) {
    __shared__ float scx[128], scy[128], scz[128];
    __shared__ float swx[128], swy[128], swz[128];
    const int b = blockIdx.x >> 6;      // 64 chunks of 256 per batch
    const int chunk = blockIdx.x & 63;
    const int t = threadIdx.x;
    if (t < K) {
        const int base = (b * K + t) * 3;
        scx[t] = cp[base + 0]; scy[t] = cp[base + 1]; scz[t] = cp[base + 2];
        swx[t] = w[base + 0];  swy[t] = w[base + 1];  swz[t] = w[base + 2];
    }
    __syncthreads();

    const int n = chunk * 256 + t;
    const size_t pbase = ((size_t)b * N + n) * 3;
    const float x = src[pbase + 0], y = src[pbase + 1], z = src[pbase + 2];

    float mind = __builtin_huge_valf();
    for (int k = 0; k < K; ++k) {
        float dx = x - scx[k], dy = y - scy[k], dz = z - scz[k];
        float d2 = dx * dx + dy * dy + dz * dz;
        mind = fminf(mind, d2);
    }
    float sum = 0.f, ax = 0.f, ay = 0.f, az = 0.f;
    for (int k = 0; k < K; ++k) {
        float dx = x - scx[k], dy = y - scy[k], dz = z - scz[k];
        float d2 = dx * dx + dy * dy + dz * dz;
        float e = __expf(2.0f * (mind - d2));   // softmax(-2*d2), max-subtracted
        sum += e;
        ax += e * swx[k]; ay += e * swy[k]; az += e * swz[k];
    }
    const float inv = 1.0f / sum;
    ax *= inv; ay *= inv; az *= inv;
    delta[pbase + 0] = ax; delta[pbase + 1] = ay; delta[pbase + 2] = az;
    outp[pbase + 0] = x + ax; outp[pbase + 1] = y + ay; outp[pbase + 2] = z + az;
}

// ---------------------------------------------------------------------------
// launch
// ---------------------------------------------------------------------------
extern "C" void kernel_launch(void* const* d_in, const int* in_sizes, int n_in,
                              void* d_out, int out_size, void* d_ws, size_t ws_size,
                              hipStream_t stream) {
    const int B = 8, N = 16384, M = 16384, F = 1024, H = 512, K = 128;
    const int BK = B * K;               // 1024 MLP rows

    const float* src       = (const float*)d_in[0];
    const float* ppf       = (const float*)d_in[1];
    const float* tgt       = (const float*)d_in[2];
    const float* tpf       = (const float*)d_in[3];
    const float* W1        = (const float*)d_in[4];
    const float* b1        = (const float*)d_in[5];
    const float* g1        = (const float*)d_in[6];
    const float* beta1     = (const float*)d_in[7];
    const float* W2        = (const float*)d_in[8];
    const float* b2        = (const float*)d_in[9];
    const float* g2        = (const float*)d_in[10];
    const float* beta2     = (const float*)d_in[11];
    const float* W3        = (const float*)d_in[12];
    const float* b3        = (const float*)d_in[13];

    float* out_output = (float*)d_out;                       // B*N*3
    float* out_delta  = out_output + (size_t)B * N * 3;      // B*N*3
    float* out_cp     = out_delta + (size_t)B * N * 3;       // B*K*3
    float* out_w      = out_cp + (size_t)B * K * 3;          // B*K*3

    char* ws = (char*)d_ws;
    int*   cp_idx = (int*)(ws + 0);
    int*   nn_idx = (int*)(ws + 4096);
    float* mu     = (float*)(ws + 8192);
    float* rstd   = (float*)(ws + 8192 + 2048);
    float* mlp_in = (float*)(ws + 16384);                            // 1024 x 2048 (8 MB)
    float* h1     = (float*)(ws + 16384 + (size_t)BK * 2 * F * 4);   // 1024 x 512  (2 MB)
    float* h2     = (float*)((char*)h1 + (size_t)BK * H * 4);        // 1024 x 512  (2 MB)

    // 1. FPS
    fps_kernel<<<B, FPS_THREADS, 0, stream>>>(src, cp_idx, out_cp, N, K);
    // 2. nearest target per control point
    nn_kernel<<<BK, 256, 0, stream>>>(tgt, out_cp, nn_idx, M);
    // 3. gather MLP input
    gather_kernel<<<BK, 256, 0, stream>>>(ppf, tpf, cp_idx, nn_idx, mlp_in, N, M, F);
    // 4. layer 1
    gemm_bias<<<dim3(H / 64, BK / 64), 256, 0, stream>>>(mlp_in, W1, b1, h1, BK, H, 2 * F);
    bn_stats<<<(H + 255) / 256, 256, 0, stream>>>(h1, mu, rstd, BK, H);
    bn_apply<<<(BK * H + 255) / 256, 256, 0, stream>>>(h1, mu, rstd, g1, beta1, BK * H, H - 1);
    // 5. layer 2
    gemm_bias<<<dim3(H / 64, BK / 64), 256, 0, stream>>>(h1, W2, b2, h2, BK, H, H);
    bn_stats<<<(H + 255) / 256, 256, 0, stream>>>(h2, mu, rstd, BK, H);
    bn_apply<<<(BK * H + 255) / 256, 256, 0, stream>>>(h2, mu, rstd, g2, beta2, BK * H, H - 1);
    // 6. head -> w
    head_kernel<<<BK / 4, 256, 0, stream>>>(h2, W3, b3, out_w, H);
    // 7. RBF interpolation -> output, delta
    rbf_kernel<<<B * (N / 256), 256, 0, stream>>>(src, out_cp, out_w, out_output, out_delta, N, K);
}

// Round 2
// 463.225 us; speedup vs baseline: 2.4017x; 2.4017x over previous
//
#include <hip/hip_runtime.h>
#include <hip/hip_bf16.h>

#define FPS_THREADS 1024
#define PTS_PER_THR 16      // 16384 / 1024

// ---------------------------------------------------------------------------
// helpers
// ---------------------------------------------------------------------------
__device__ inline unsigned long long shfl_down_u64(unsigned long long x, int off) {
    unsigned int lo = (unsigned int)(x & 0xFFFFFFFFull);
    unsigned int hi = (unsigned int)(x >> 32);
    lo = __shfl_down(lo, off, 64);
    hi = __shfl_down(hi, off, 64);
    return (((unsigned long long)hi) << 32) | lo;
}

// ---------------------------------------------------------------------------
// 1. Farthest point sampling: one block per batch, points cached in registers
// ---------------------------------------------------------------------------
__global__ __launch_bounds__(FPS_THREADS) void fps_kernel(
        const float* __restrict__ src, int* __restrict__ cp_idx,
        float* __restrict__ out_cp, int N, int K) {
    const int b = blockIdx.x;
    const int t = threadIdx.x;
    const float* p = src + (size_t)b * N * 3;

    float px[PTS_PER_THR], py[PTS_PER_THR], pz[PTS_PER_THR], dmin[PTS_PER_THR];
#pragma unroll
    for (int i = 0; i < PTS_PER_THR; ++i) {
        int j = i * FPS_THREADS + t;
        px[i] = p[j * 3 + 0];
        py[i] = p[j * 3 + 1];
        pz[i] = p[j * 3 + 2];
        dmin[i] = __builtin_huge_valf();
    }

    __shared__ unsigned long long red[FPS_THREADS / 64];
    __shared__ float sC[3];

    if (t == 0) {
        cp_idx[b * K + 0] = 0;
        float fx = p[0], fy = p[1], fz = p[2];
        out_cp[(b * K + 0) * 3 + 0] = fx;
        out_cp[(b * K + 0) * 3 + 1] = fy;
        out_cp[(b * K + 0) * 3 + 2] = fz;
        sC[0] = fx; sC[1] = fy; sC[2] = fz;
    }
    __syncthreads();

    for (int k = 1; k < K; ++k) {
        const float cx = sC[0], cy = sC[1], cz = sC[2];
        unsigned long long best = 0ull;
#pragma unroll
        for (int i = 0; i < PTS_PER_THR; ++i) {
            float dx = px[i] - cx, dy = py[i] - cy, dz = pz[i] - cz;
            float d = dx * dx + dy * dy + dz * dz;
            dmin[i] = fminf(dmin[i], d);
            unsigned int fb = __float_as_uint(dmin[i]);   // nonneg -> monotonic bits
            unsigned int j = (unsigned int)(i * FPS_THREADS + t);
            unsigned long long pk =
                (((unsigned long long)fb) << 32) | (0xFFFFFFFFu - j); // tie -> smaller j
            best = (pk > best) ? pk : best;
        }
#pragma unroll
        for (int off = 32; off >= 1; off >>= 1) {
            unsigned long long o = shfl_down_u64(best, off);
            best = (o > best) ? o : best;
        }
        if ((t & 63) == 0) red[t >> 6] = best;
        __syncthreads();
        if (t == 0) {
            unsigned long long bb = red[0];
#pragma unroll
            for (int wv = 1; wv < FPS_THREADS / 64; ++wv)
                bb = (red[wv] > bb) ? red[wv] : bb;
            int far = (int)(0xFFFFFFFFu - (unsigned int)(bb & 0xFFFFFFFFull));
            cp_idx[b * K + k] = far;
            float fx = p[far * 3 + 0], fy = p[far * 3 + 1], fz = p[far * 3 + 2];
            out_cp[(b * K + k) * 3 + 0] = fx;
            out_cp[(b * K + k) * 3 + 1] = fy;
            out_cp[(b * K + k) * 3 + 2] = fz;
            sC[0] = fx; sC[1] = fy; sC[2] = fz;
        }
        __syncthreads();
    }
}

// ---------------------------------------------------------------------------
// 2. Nearest target point per control point: one block per (b,k)
// ---------------------------------------------------------------------------
__global__ __launch_bounds__(256) void nn_kernel(
        const float* __restrict__ tgt, const float* __restrict__ cp,
        int* __restrict__ nn_idx, int M) {
    const int bk = blockIdx.x;          // b*K + k
    const int b = bk >> 7;              // K = 128
    const int t = threadIdx.x;
    const float* tp = tgt + (size_t)b * M * 3;

    const float cx = cp[bk * 3 + 0], cy = cp[bk * 3 + 1], cz = cp[bk * 3 + 2];
    const float cp2 = cx * cx + cy * cy + cz * cz;

    unsigned long long best = ~0ull;
    for (int m = t; m < M; m += 256) {
        float tx = tp[m * 3 + 0], ty = tp[m * 3 + 1], tz = tp[m * 3 + 2];
        float tg2 = tx * tx + ty * ty + tz * tz;
        float cross = cx * tx + cy * ty + cz * tz;
        float v = (cp2 + tg2) - 2.0f * cross;
        unsigned int fb = __float_as_uint(v);
        fb = (fb & 0x80000000u) ? ~fb : (fb | 0x80000000u); // order-preserving flip
        unsigned long long pk = (((unsigned long long)fb) << 32) | (unsigned int)m;
        best = (pk < best) ? pk : best;   // min value, tie -> smaller m
    }
#pragma unroll
    for (int off = 32; off >= 1; off >>= 1) {
        unsigned long long o = shfl_down_u64(best, off);
        best = (o < best) ? o : best;
    }
    __shared__ unsigned long long red[4];
    if ((t & 63) == 0) red[t >> 6] = best;
    __syncthreads();
    if (t == 0) {
        unsigned long long bb = red[0];
        for (int wv = 1; wv < 4; ++wv) bb = (red[wv] < bb) ? red[wv] : bb;
        nn_idx[bk] = (int)(bb & 0xFFFFFFFFull);
    }
}

// ---------------------------------------------------------------------------
// 3. Gather [control_feats | tgt_local_feats] -> mlp_in (B*K, 2F)
// ---------------------------------------------------------------------------
__global__ __launch_bounds__(256) void gather_kernel(
        const float* __restrict__ src_feats, const float* __restrict__ tgt_feats,
        const int* __restrict__ cp_idx, const int* __restrict__ nn_idx,
        float* __restrict__ mlp_in, int N, int M, int F) {
    const int r = blockIdx.x;           // b*K + k
    const int b = r >> 7;
    const int t = threadIdx.x;
    const float4* a = reinterpret_cast<const float4*>(
        src_feats + ((size_t)b * N + cp_idx[r]) * F);
    const float4* c = reinterpret_cast<const float4*>(
        tgt_feats + ((size_t)b * M + nn_idx[r]) * F);
    float4* o = reinterpret_cast<float4*>(mlp_in + (size_t)r * 2 * F);
    o[t] = a[t];            // F/4 = 256 = blockDim
    o[256 + t] = c[t];
}

// ---------------------------------------------------------------------------
// 4. f32 tiled GEMM with bias: C(MxN) = A(MxK) @ B(KxN) + bias
//    BM=BN=64, BK=16, 256 threads, 4x4 per thread
// ---------------------------------------------------------------------------
__global__ __launch_bounds__(256) void gemm_bias(
        const float* __restrict__ A, const float* __restrict__ B,
        const float* __restrict__ bias, float* __restrict__ C,
        int M, int N, int K) {
    __shared__ float As[16][68];
    __shared__ float Bs[16][68];
    const int tid = threadIdx.x;
    const int row0 = blockIdx.y * 64;
    const int col0 = blockIdx.x * 64;

    const int tr = (tid >> 4) * 4;      // 0..60
    const int tc = (tid & 15) * 4;      // 0..60
    const int arow = tid >> 2, ak4 = (tid & 3) * 4;
    const int brow = tid >> 4, bc4 = (tid & 15) * 4;

    float acc[4][4];
#pragma unroll
    for (int i = 0; i < 4; ++i)
#pragma unroll
        for (int j = 0; j < 4; ++j) acc[i][j] = 0.f;

    for (int kt = 0; kt < K; kt += 16) {
        float4 av = *reinterpret_cast<const float4*>(
            &A[(size_t)(row0 + arow) * K + kt + ak4]);
        float4 bv = *reinterpret_cast<const float4*>(
            &B[(size_t)(kt + brow) * N + col0 + bc4]);
        __syncthreads();
        As[ak4 + 0][arow] = av.x;
        As[ak4 + 1][arow] = av.y;
        As[ak4 + 2][arow] = av.z;
        As[ak4 + 3][arow] = av.w;
        *reinterpret_cast<float4*>(&Bs[brow][bc4]) = bv;
        __syncthreads();
#pragma unroll
        for (int kk = 0; kk < 16; ++kk) {
            float a0 = As[kk][tr + 0], a1 = As[kk][tr + 1];
            float a2 = As[kk][tr + 2], a3 = As[kk][tr + 3];
            float b0 = Bs[kk][tc + 0], b1 = Bs[kk][tc + 1];
            float b2 = Bs[kk][tc + 2], b3 = Bs[kk][tc + 3];
            acc[0][0] += a0 * b0; acc[0][1] += a0 * b1; acc[0][2] += a0 * b2; acc[0][3] += a0 * b3;
            acc[1][0] += a1 * b0; acc[1][1] += a1 * b1; acc[1][2] += a1 * b2; acc[1][3] += a1 * b3;
            acc[2][0] += a2 * b0; acc[2][1] += a2 * b1; acc[2][2] += a2 * b2; acc[2][3] += a2 * b3;
            acc[3][0] += a3 * b0; acc[3][1] += a3 * b1; acc[3][2] += a3 * b2; acc[3][3] += a3 * b3;
        }
    }
#pragma unroll
    for (int i = 0; i < 4; ++i) {
        float* crow = &C[(size_t)(row0 + tr + i) * N + col0 + tc];
#pragma unroll
        for (int j = 0; j < 4; ++j) crow[j] = acc[i][j] + bias[col0 + tc + j];
    }
}

// ---------------------------------------------------------------------------
// 5a. BN partial stats: one-pass sum/sumsq per 32-row chunk (coalesced)
//     grid.x = nchunks (32), block = 256
// ---------------------------------------------------------------------------
__global__ __launch_bounds__(256) void bn_partial(
        const float* __restrict__ Hm, float* __restrict__ psum,
        float* __restrict__ psumsq, int Ncols) {
    const int chunk = blockIdx.x;
    const int t = threadIdx.x;
    const float* base = Hm + (size_t)chunk * 32 * Ncols;
    for (int c = t; c < Ncols; c += 256) {
        float s = 0.f, ss = 0.f;
#pragma unroll 8
        for (int r = 0; r < 32; ++r) {
            float x = base[(size_t)r * Ncols + c];
            s += x;
            ss += x * x;
        }
        psum[chunk * Ncols + c] = s;
        psumsq[chunk * Ncols + c] = ss;
    }
}

// ---------------------------------------------------------------------------
// 5b. BN finalize: fold partials -> mu, rstd
// ---------------------------------------------------------------------------
__global__ __launch_bounds__(256) void bn_finalize(
        const float* __restrict__ psum, const float* __restrict__ psumsq,
        float* __restrict__ mu, float* __restrict__ rstd,
        int Ncols, int nchunks, float invM) {
    const int c = blockIdx.x * 256 + threadIdx.x;
    if (c >= Ncols) return;
    float s = 0.f, ss = 0.f;
    for (int i = 0; i < nchunks; ++i) {
        s += psum[i * Ncols + c];
        ss += psumsq[i * Ncols + c];
    }
    const float m = s * invM;
    mu[c] = m;
    rstd[c] = rsqrtf(fmaxf(ss * invM - m * m, 0.f) + 1e-5f);
}

// ---------------------------------------------------------------------------
// 6. BN apply + ReLU (in place)
// ---------------------------------------------------------------------------
__global__ __launch_bounds__(256) void bn_apply(
        float* __restrict__ Hm, const float* __restrict__ mu,
        const float* __restrict__ rstd, const float* __restrict__ g,
        const float* __restrict__ beta, int total, int NcolsMask) {
    const int i = blockIdx.x * 256 + threadIdx.x;
    if (i < total) {
        const int c = i & NcolsMask;
        float x = Hm[i];
        x = g[c] * (x - mu[c]) * rstd[c] + beta[c];
        Hm[i] = fmaxf(x, 0.f);
    }
}

// ---------------------------------------------------------------------------
// 7. Head: w (1024x3) = h2 (1024x512) @ W3 (512x3) + b3 ; one wave per row
// ---------------------------------------------------------------------------
__global__ __launch_bounds__(256) void head_kernel(
        const float* __restrict__ Hm, const float* __restrict__ W3,
        const float* __restrict__ b3, float* __restrict__ w_out, int Ncols) {
    const int row = blockIdx.x * 4 + (threadIdx.x >> 6);
    const int lane = threadIdx.x & 63;
    float a0 = 0.f, a1 = 0.f, a2 = 0.f;
    for (int c = lane; c < Ncols; c += 64) {
        float h = Hm[(size_t)row * Ncols + c];
        a0 += h * W3[c * 3 + 0];
        a1 += h * W3[c * 3 + 1];
        a2 += h * W3[c * 3 + 2];
    }
#pragma unroll
    for (int off = 32; off >= 1; off >>= 1) {
        a0 += __shfl_down(a0, off, 64);
        a1 += __shfl_down(a1, off, 64);
        a2 += __shfl_down(a2, off, 64);
    }
    if (lane == 0) {
        w_out[row * 3 + 0] = a0 + b3[0];
        w_out[row * 3 + 1] = a1 + b3[1];
        w_out[row * 3 + 2] = a2 + b3[2];
    }
}

// ---------------------------------------------------------------------------
// 8. RBF softmax interpolation: output = src + (softmax(-2*d2) @ w)
// ---------------------------------------------------------------------------
__global__ __launch_bounds__(256) void rbf_kernel(
        const float* __restrict__ src, const float* __restrict__ cp,
        const float* __restrict__ w, float* __restrict__ outp,
        float* __restrict__ delta, int N, int K) {
    __shared__ float scx[128], scy[128], scz[128];
    __shared__ float swx[128], swy[128], swz[128];
    const int b = blockIdx.x >> 6;      // 64 chunks of 256 per batch
    const int chunk = blockIdx.x & 63;
    const int t = threadIdx.x;
    if (t < K) {
        const int base = (b * K + t) * 3;
        scx[t] = cp[base + 0]; scy[t] = cp[base + 1]; scz[t] = cp[base + 2];
        swx[t] = w[base + 0];  swy[t] = w[base + 1];  swz[t] = w[base + 2];
    }
    __syncthreads();

    const int n = chunk * 256 + t;
    const size_t pbase = ((size_t)b * N + n) * 3;
    const float x = src[pbase + 0], y = src[pbase + 1], z = src[pbase + 2];

    float mind = __builtin_huge_valf();
    for (int k = 0; k < K; ++k) {
        float dx = x - scx[k], dy = y - scy[k], dz = z - scz[k];
        float d2 = dx * dx + dy * dy + dz * dz;
        mind = fminf(mind, d2);
    }
    float sum = 0.f, ax = 0.f, ay = 0.f, az = 0.f;
    for (int k = 0; k < K; ++k) {
        float dx = x - scx[k], dy = y - scy[k], dz = z - scz[k];
        float d2 = dx * dx + dy * dy + dz * dz;
        float e = __expf(2.0f * (mind - d2));   // softmax(-2*d2), max-subtracted
        sum += e;
        ax += e * swx[k]; ay += e * swy[k]; az += e * swz[k];
    }
    const float inv = 1.0f / sum;
    ax *= inv; ay *= inv; az *= inv;
    delta[pbase + 0] = ax; delta[pbase + 1] = ay; delta[pbase + 2] = az;
    outp[pbase + 0] = x + ax; outp[pbase + 1] = y + ay; outp[pbase + 2] = z + az;
}

// ---------------------------------------------------------------------------
// launch
// ---------------------------------------------------------------------------
extern "C" void kernel_launch(void* const* d_in, const int* in_sizes, int n_in,
                              void* d_out, int out_size, void* d_ws, size_t ws_size,
                              hipStream_t stream) {
    const int B = 8, N = 16384, M = 16384, F = 1024, H = 512, K = 128;
    const int BK = B * K;               // 1024 MLP rows
    const int NCHUNKS = 32;             // 1024 rows / 32

    const float* src       = (const float*)d_in[0];
    const float* ppf       = (const float*)d_in[1];
    const float* tgt       = (const float*)d_in[2];
    const float* tpf       = (const float*)d_in[3];
    const float* W1        = (const float*)d_in[4];
    const float* b1        = (const float*)d_in[5];
    const float* g1        = (const float*)d_in[6];
    const float* beta1     = (const float*)d_in[7];
    const float* W2        = (const float*)d_in[8];
    const float* b2        = (const float*)d_in[9];
    const float* g2        = (const float*)d_in[10];
    const float* beta2     = (const float*)d_in[11];
    const float* W3        = (const float*)d_in[12];
    const float* b3        = (const float*)d_in[13];

    float* out_output = (float*)d_out;                       // B*N*3
    float* out_delta  = out_output + (size_t)B * N * 3;      // B*N*3
    float* out_cp     = out_delta + (size_t)B * N * 3;       // B*K*3
    float* out_w      = out_cp + (size_t)B * K * 3;          // B*K*3

    char* ws = (char*)d_ws;
    int*   cp_idx = (int*)(ws + 0);
    int*   nn_idx = (int*)(ws + 4096);
    float* mu     = (float*)(ws + 8192);
    float* rstd   = (float*)(ws + 8192 + 2048);
    float* psum   = (float*)(ws + 16384);                    // 32 x 512 (64 KB)
    float* psumsq = (float*)(ws + 16384 + 65536);            // 32 x 512 (64 KB)
    char*  ws2    = ws + 16384 + 2 * 65536;
    float* mlp_in = (float*)(ws2);                           // 1024 x 2048 (8 MB)
    float* h1     = (float*)(ws2 + (size_t)BK * 2 * F * 4);  // 1024 x 512  (2 MB)
    float* h2     = (float*)((char*)h1 + (size_t)BK * H * 4);// 1024 x 512  (2 MB)

    // 1. FPS
    fps_kernel<<<B, FPS_THREADS, 0, stream>>>(src, cp_idx, out_cp, N, K);
    // 2. nearest target per control point
    nn_kernel<<<BK, 256, 0, stream>>>(tgt, out_cp, nn_idx, M);
    // 3. gather MLP input
    gather_kernel<<<BK, 256, 0, stream>>>(ppf, tpf, cp_idx, nn_idx, mlp_in, N, M, F);
    // 4. layer 1
    gemm_bias<<<dim3(H / 64, BK / 64), 256, 0, stream>>>(mlp_in, W1, b1, h1, BK, H, 2 * F);
    bn_partial<<<NCHUNKS, 256, 0, stream>>>(h1, psum, psumsq, H);
    bn_finalize<<<(H + 255) / 256, 256, 0, stream>>>(psum, psumsq, mu, rstd, H, NCHUNKS, 1.0f / BK);
    bn_apply<<<(BK * H + 255) / 256, 256, 0, stream>>>(h1, mu, rstd, g1, beta1, BK * H, H - 1);
    // 5. layer 2
    gemm_bias<<<dim3(H / 64, BK / 64), 256, 0, stream>>>(h1, W2, b2, h2, BK, H, H);
    bn_partial<<<NCHUNKS, 256, 0, stream>>>(h2, psum, psumsq, H);
    bn_finalize<<<(H + 255) / 256, 256, 0, stream>>>(psum, psumsq, mu, rstd, H, NCHUNKS, 1.0f / BK);
    bn_apply<<<(BK * H + 255) / 256, 256, 0, stream>>>(h2, mu, rstd, g2, beta2, BK * H, H - 1);
    // 6. head -> w
    head_kernel<<<BK / 4, 256, 0, stream>>>(h2, W3, b3, out_w, H);
    // 7. RBF interpolation -> output, delta
    rbf_kernel<<<B * (N / 256), 256, 0, stream>>>(src, out_cp, out_w, out_output, out_delta, N, K);
}